// Round 2
// baseline (197.834 us; speedup 1.0000x reference)
//
#include <hip/hip_runtime.h>
#include <math.h>

#define D 256
#define B 16
#define L 8
#define N 128

#define VSTR 20   // vin_t row stride in floats (16 data + 4 pad, 16B-aligned)
#define RSTR 68   // red row stride in floats (64 data + 4 pad)

static constexpr float LAMBDA_ASYNC = 0.08f;
static constexpr float LAMBDA_TAU   = 0.12f;

// ws layout (floats): acc[8][B*D] then fired[8][N]
#define WS_ACC(l)    (ws + (size_t)(l) * (B * D))
#define WS_FIRED(l)  (ws + (size_t)8 * (B * D) + (size_t)(l) * N)

// Grid: 512 blocks = node*4 + e-quarter (64 e each). Block: 256 threads.
// Thread: eg = t&15 -> 4 consecutive e; dg = t>>4 -> d in {dg, dg+16, ..., dg+240}.
__global__ __launch_bounds__(256, 2) void layer_kernel(
    const float* __restrict__ X,      // B*D (l==0 input)
    const float* __restrict__ W,      // L*N*D*D
    const float* __restrict__ bias,   // L*N*D
    const float* __restrict__ S,      // L*N*D
    const float* __restrict__ rho,    // L*N
    const float* __restrict__ boost,  // L*N
    const int*  __restrict__ tb,      // scalar
    float* __restrict__ ws,
    int l)
{
    __shared__ float vin_t[D * VSTR];   // [d][b] transposed, 20 KB
    __shared__ float red[64 * RSTR];    // cross-wave partials, ~17.4 KB
    __shared__ float sh[8];

    const int t  = threadIdx.x;
    const int n  = blockIdx.x >> 2;
    const int e0 = (blockIdx.x & 3) * 64;

    float* acc_cur   = WS_ACC(l);
    float* fired_cur = WS_FIRED(l);

    // ---- 1) previous-layer fired count -> scale; pick vin source
    float scale;
    bool has_input;
    const float* src;
    if (l == 0) {
        scale = 1.0f; has_input = true; src = X;
    } else {
        const float* fired_prev = WS_FIRED(l - 1);
        float f = (t < N) ? fired_prev[t] : 0.0f;
        #pragma unroll
        for (int o = 32; o > 0; o >>= 1) f += __shfl_down(f, o);
        if ((t & 63) == 0) sh[t >> 6] = f;
        __syncthreads();
        const float cnt_raw = sh[0] + sh[1] + sh[2] + sh[3];
        has_input = (cnt_raw > 0.0f);
        scale = expf(-LAMBDA_ASYNC) / fmaxf(cnt_raw, 1.0f);
        src = WS_ACC(l - 1);
    }

    // ---- 2) stage scaled V_in transposed: thread t holds all 16 b for d == t
    float vr[16];
    #pragma unroll
    for (int r = 0; r < 16; ++r) vr[r] = src[r * D + t] * scale;  // coalesced
    float cs = 0.0f;
    #pragma unroll
    for (int r = 0; r < 16; ++r) cs += vr[r];                     // colsum[d=t]
    #pragma unroll
    for (int j = 0; j < 4; ++j) {
        float4 v = make_float4(vr[4*j], vr[4*j+1], vr[4*j+2], vr[4*j+3]);
        *(float4*)&vin_t[t * VSTR + 4 * j] = v;
    }

    // ---- 3) firing decision: sdot = <colsum, S_n>/B  (block-uniform result)
    {
        float p = cs * S[(size_t)(l * N + n) * D + t];
        #pragma unroll
        for (int o = 32; o > 0; o >>= 1) p += __shfl_down(p, o);
        if ((t & 63) == 0) sh[4 + (t >> 6)] = p;
    }
    __syncthreads();   // covers sh[4..7] AND vin_t visibility for the main loop
    {
        const float sdot = (sh[4] + sh[5] + sh[6] + sh[7]) * (1.0f / 16.0f);
        const float tau  = 0.5f * expf(LAMBDA_TAU * ((float)(l + 1) - (float)tb[0]));
        const bool fired = (rho[l * N + n] + sdot + boost[l * N + n] >= tau) && has_input;
        if (e0 == 0 && t == 0) fired_cur[n] = fired ? 1.0f : 0.0f;
        if (!fired) return;   // block-uniform early exit: skip W stream entirely
    }

    // ---- 4) main loop: acc[b].{x..w} over e = e0+eg*4+{0..3}, d = dg+16k
    const int eg = t & 15;
    const int dg = t >> 4;
    const float* wbase = W + ((size_t)(l * N + n) * D + (size_t)dg) * D + (e0 + eg * 4);

    float4 acc[16];
    #pragma unroll
    for (int b = 0; b < 16; ++b) acc[b] = make_float4(0.f, 0.f, 0.f, 0.f);

    float4 wbuf[2][4];
    #pragma unroll
    for (int kk = 0; kk < 4; ++kk)
        wbuf[0][kk] = *(const float4*)(wbase + (size_t)(16 * kk) * D);

    #pragma unroll
    for (int c = 0; c < 4; ++c) {
        const int cur = c & 1, nxt = cur ^ 1;
        if (c < 3) {
            #pragma unroll
            for (int kk = 0; kk < 4; ++kk)
                wbuf[nxt][kk] = *(const float4*)(wbase + (size_t)(16 * (4 * (c + 1) + kk)) * D);
        }
        #pragma unroll
        for (int kk = 0; kk < 4; ++kk) {
            const int d = dg + 16 * (4 * c + kk);
            const float4 wv = wbuf[cur][kk];
            #pragma unroll
            for (int jj = 0; jj < 4; ++jj) {
                const float4 v = *(const float4*)&vin_t[d * VSTR + 4 * jj];
                acc[4*jj+0].x = fmaf(wv.x, v.x, acc[4*jj+0].x);
                acc[4*jj+0].y = fmaf(wv.y, v.x, acc[4*jj+0].y);
                acc[4*jj+0].z = fmaf(wv.z, v.x, acc[4*jj+0].z);
                acc[4*jj+0].w = fmaf(wv.w, v.x, acc[4*jj+0].w);
                acc[4*jj+1].x = fmaf(wv.x, v.y, acc[4*jj+1].x);
                acc[4*jj+1].y = fmaf(wv.y, v.y, acc[4*jj+1].y);
                acc[4*jj+1].z = fmaf(wv.z, v.y, acc[4*jj+1].z);
                acc[4*jj+1].w = fmaf(wv.w, v.y, acc[4*jj+1].w);
                acc[4*jj+2].x = fmaf(wv.x, v.z, acc[4*jj+2].x);
                acc[4*jj+2].y = fmaf(wv.y, v.z, acc[4*jj+2].y);
                acc[4*jj+2].z = fmaf(wv.z, v.z, acc[4*jj+2].z);
                acc[4*jj+2].w = fmaf(wv.w, v.z, acc[4*jj+2].w);
                acc[4*jj+3].x = fmaf(wv.x, v.w, acc[4*jj+3].x);
                acc[4*jj+3].y = fmaf(wv.y, v.w, acc[4*jj+3].y);
                acc[4*jj+3].z = fmaf(wv.z, v.w, acc[4*jj+3].z);
                acc[4*jj+3].w = fmaf(wv.w, v.w, acc[4*jj+3].w);
            }
        }
    }

    // ---- 5) reduce over dg: xor16 + xor32 within wave (dg&3), LDS across waves
    #pragma unroll
    for (int b = 0; b < 16; ++b) {
        acc[b].x += __shfl_xor(acc[b].x, 16); acc[b].y += __shfl_xor(acc[b].y, 16);
        acc[b].z += __shfl_xor(acc[b].z, 16); acc[b].w += __shfl_xor(acc[b].w, 16);
        acc[b].x += __shfl_xor(acc[b].x, 32); acc[b].y += __shfl_xor(acc[b].y, 32);
        acc[b].z += __shfl_xor(acc[b].z, 32); acc[b].w += __shfl_xor(acc[b].w, 32);
    }
    if ((dg & 3) == 0) {                  // one writer per (wave, eg)
        const int w = dg >> 2;
        float* rr = &red[(w * 16 + eg) * RSTR];
        #pragma unroll
        for (int b = 0; b < 16; ++b) *(float4*)(rr + b * 4) = acc[b];
    }
    __syncthreads();

    // ---- 6) epilogue: thread = (eg2, b2); sum 4 wave-partials, bias, tanh, atomic
    {
        const int eg2 = t & 15;
        const int b2  = t >> 4;
        float4 s = make_float4(0.f, 0.f, 0.f, 0.f);
        #pragma unroll
        for (int w = 0; w < 4; ++w) {
            const float4 rv = *(const float4*)&red[(w * 16 + eg2) * RSTR + b2 * 4];
            s.x += rv.x; s.y += rv.y; s.z += rv.z; s.w += rv.w;
        }
        const float4 bv = *(const float4*)(bias + (size_t)(l * N + n) * D + e0 + eg2 * 4);
        float* op = acc_cur + (size_t)b2 * D + e0 + eg2 * 4;
        atomicAdd(op + 0, tanhf(s.x + bv.x));
        atomicAdd(op + 1, tanhf(s.y + bv.y));
        atomicAdd(op + 2, tanhf(s.z + bv.z));
        atomicAdd(op + 3, tanhf(s.w + bv.w));
    }
}

// out[b][e] = acc7[b][e] / max(cnt7, 1)
__global__ __launch_bounds__(256) void finalize_kernel(
    const float* __restrict__ ws, float* __restrict__ out)
{
    __shared__ float sh[4];
    const int t = threadIdx.x;
    const float* fired7 = ws + (size_t)8 * (B * D) + (size_t)7 * N;
    float f = (t < N) ? fired7[t] : 0.0f;
    #pragma unroll
    for (int o = 32; o > 0; o >>= 1) f += __shfl_down(f, o);
    if ((t & 63) == 0) sh[t >> 6] = f;
    __syncthreads();
    const float inv = 1.0f / fmaxf(sh[0] + sh[1] + sh[2] + sh[3], 1.0f);
    const float* acc7 = ws + (size_t)7 * (B * D);
    for (int i = t; i < B * D; i += 256) out[i] = acc7[i] * inv;
}

extern "C" void kernel_launch(void* const* d_in, const int* in_sizes, int n_in,
                              void* d_out, int out_size, void* d_ws, size_t ws_size,
                              hipStream_t stream)
{
    const float* X     = (const float*)d_in[0];
    const float* W     = (const float*)d_in[1];
    const float* bias  = (const float*)d_in[2];
    const float* S     = (const float*)d_in[3];
    const float* rho   = (const float*)d_in[4];
    const float* boost = (const float*)d_in[5];
    const int*   tb    = (const int*)d_in[6];
    float* out = (float*)d_out;
    float* ws  = (float*)d_ws;

    const size_t ws_used = ((size_t)8 * B * D + (size_t)8 * N) * sizeof(float);
    hipMemsetAsync(d_ws, 0, ws_used, stream);

    for (int l = 0; l < L; ++l) {
        layer_kernel<<<dim3(N * 4), dim3(256), 0, stream>>>(
            X, W, bias, S, rho, boost, tb, ws, l);
    }
    finalize_kernel<<<dim3(1), dim3(256), 0, stream>>>(ws, out);
}